// Round 15
// baseline (1070.414 us; speedup 1.0000x reference)
//
#include <hip/hip_runtime.h>
#include <hip/hip_bf16.h>

typedef __hip_bfloat16 bf16;
typedef __attribute__((ext_vector_type(4))) short s16x4;
typedef __attribute__((ext_vector_type(8))) short short8;
typedef __attribute__((ext_vector_type(8))) __bf16 bf16x8;
typedef __attribute__((ext_vector_type(4))) float f32x4;

__device__ __forceinline__ float s2f(short s) {
  return __builtin_bit_cast(float, (unsigned)((unsigned short)s) << 16);
}
__device__ __forceinline__ short f2s(float f) {
  return __builtin_bit_cast(short, __float2bfloat16(f));
}

__device__ __forceinline__ void gl16(const bf16* g, bf16* l) {
  __builtin_amdgcn_global_load_lds(
      (const __attribute__((address_space(1))) void*)g,
      (__attribute__((address_space(3))) void*)l, 16, 0, 0);
}

// ---------------------------------------------------------------- zero fill (zpage)
__global__ void zerofill(float* p, int n) {
  int i = blockIdx.x * 256 + threadIdx.x;
  if (i < n) p[i] = 0.f;
}

// ---------------------------------------------------------------- layer 1: 3->64, fp32 NCHW in, bf16 NHWC out
__global__ __launch_bounds__(256) void conv1_first(
    const float* __restrict__ x, const float* __restrict__ w,
    const float* __restrict__ b, bf16* __restrict__ out) {
  __shared__ float it[3][18][18];
  __shared__ float wl2[27 * 64];
  __shared__ float bl[64];
  const int tid = threadIdx.x;
  const int n = blockIdx.z;
  const int h0 = blockIdx.y * 16, w0 = blockIdx.x * 16;
  for (int i = tid; i < 1728; i += 256) {
    int jj = i >> 6, co = i & 63;
    wl2[i] = w[co * 27 + jj];
  }
  if (tid < 64) bl[tid] = b[tid];
  for (int i = tid; i < 972; i += 256) {
    int ci = i / 324; int r = i - ci * 324; int ty = r / 18, tx = r - ty * 18;
    int hh = h0 - 1 + ty, ww = w0 - 1 + tx;
    float v = 0.f;
    if (hh >= 0 && hh < 224 && ww >= 0 && ww < 224)
      v = x[((long)n * 3 + ci) * 50176 + hh * 224 + ww];
    it[ci][ty][tx] = v;
  }
  __syncthreads();
  const int ty = tid >> 4, tx = tid & 15;
  long ob = (((long)n * 224 + h0 + ty) * 224 + (w0 + tx)) * 64;
  for (int cog = 0; cog < 4; ++cog) {
    f32x4 a4[4];
    #pragma unroll
    for (int q = 0; q < 4; ++q) a4[q] = *(const f32x4*)&bl[cog * 16 + q * 4];
    #pragma unroll
    for (int jj = 0; jj < 27; ++jj) {
      const int ci = jj / 9, r = jj - ci * 9, kh = r / 3, kw = r - kh * 3;
      float v = it[ci][ty + kh][tx + kw];
      const f32x4* wp4 = (const f32x4*)&wl2[jj * 64 + cog * 16];
      #pragma unroll
      for (int q = 0; q < 4; ++q) a4[q] += v * wp4[q];
    }
    short8 s0, s1;
    #pragma unroll
    for (int u = 0; u < 4; ++u) {
      s0[u] = f2s(fmaxf(a4[0][u], 0.f));
      s0[4 + u] = f2s(fmaxf(a4[1][u], 0.f));
      s1[u] = f2s(fmaxf(a4[2][u], 0.f));
      s1[4 + u] = f2s(fmaxf(a4[3][u], 0.f));
    }
    *(short8*)(out + ob + cog * 16) = s0;
    *(short8*)(out + ob + cog * 16 + 8) = s1;
  }
}

// ---------------------------------------------------------------- fused weight repack (all 12 MFMA conv layers)
struct RepackMeta {
  const float* src[12];
  long dstOff[12];
  int cinM1[12];
  int cshift[12];
  int cout[12];
};

__global__ __launch_bounds__(256) void repack_all(RepackMeta m, bf16* __restrict__ blob) {
  const int li = blockIdx.y;
  const int co = blockIdx.x;
  if (co >= m.cout[li]) return;
  const int cs = m.cshift[li];
  const int cinM1 = m.cinM1[li];
  const int K = 9 << cs;
  const float* src = m.src[li] + (long)co * (cinM1 + 1) * 9;
  bf16* dst = blob + m.dstOff[li] + (long)co * K;
  for (int k = threadIdx.x; k < K; k += 256) {
    int pos = k >> cs;
    int ci = k & cinM1;
    dst[k] = __float2bfloat16(src[ci * 9 + pos]);
  }
}

// ---------------------------------------------------------------- conv_halo64: L0 (224x224, Cin=Cout=64) + FUSED 2x2 maxpool
__global__ __launch_bounds__(256) void conv_halo64(
    const bf16* __restrict__ in, const bf16* __restrict__ wp,
    const float* __restrict__ bias, bf16* __restrict__ out,
    const bf16* __restrict__ zp) {
  __shared__ bf16 tA[10 * 34 * 64];   // 43520 B; row stride 34*64=2176 elems (4352 B)
  __shared__ bf16 tB[9 * 64 * 64];    // 73728 B; 9 pos-blocks of [col][64]
  const int tid = threadIdx.x;
  const int lane = tid & 63, wv = tid >> 6;
  const int n = blockIdx.z;
  const int h0 = blockIdx.y * 8, w0 = blockIdx.x * 32;

  #pragma unroll
  for (int i = 0; i < 11; ++i) {
    int cid = i * 256 + tid;
    if (cid < 2720) {
      int row = cid / 272;
      int rem = cid - row * 272;
      int w = rem >> 3, j = rem & 7;
      int hg = h0 - 1 + row, wg = w0 - 1 + w;
      bool ok = (hg >= 0) & (hg < 224) & (wg >= 0) & (wg < 224);
      const bf16* src = ok ? (in + (((long)n * 224 + hg) * 224 + wg) * 64 + ((j ^ (w & 7)) << 3))
                           : zp;
      gl16(src, tA + (long)cid * 8);
    }
  }
  {
    const int colB = tid >> 3;
    const int colx = ((tid & 7) ^ (colB & 7)) * 8;
    const bf16* s0 = wp + (long)colB * 576 + colx;
    const bf16* s1 = wp + (long)(colB + 32) * 576 + colx;
    #pragma unroll
    for (int p = 0; p < 9; ++p) {
      gl16(s0 + p * 64, tB + p * 4096 + tid * 8);
      gl16(s1 + p * 64, tB + p * 4096 + 2048 + tid * 8);
    }
  }
  __syncthreads();

  f32x4 acc[4][4];
  #pragma unroll
  for (int m = 0; m < 4; ++m)
    #pragma unroll
    for (int n2 = 0; n2 < 4; ++n2) acc[m][n2] = (f32x4){0.f, 0.f, 0.f, 0.f};

  for (int pos = 0; pos < 9; ++pos) {
    const int dh = pos / 3, dw = pos - (pos / 3) * 3;
    #pragma unroll
    for (int ks = 0; ks < 2; ++ks) {
      const int kb = ks * 64 + (lane >> 4) * 16;
      bf16x8 af[4], bfv[4];
      #pragma unroll
      for (int m = 0; m < 4; ++m) {
        int p = wv * 64 + m * 16 + (lane & 15);
        int hl = (p >> 5) + dh, wl = (p & 31) + dw;
        af[m] = *(const bf16x8*)((const char*)tA + hl * 4352 + wl * 128 + (kb ^ ((wl & 7) << 4)));
      }
      #pragma unroll
      for (int n2 = 0; n2 < 4; ++n2) {
        int c = n2 * 16 + (lane & 15);
        bfv[n2] = *(const bf16x8*)((const char*)tB + pos * 8192 + c * 128 + (kb ^ ((c & 7) << 4)));
      }
      #pragma unroll
      for (int m = 0; m < 4; ++m)
        #pragma unroll
        for (int n2 = 0; n2 < 4; ++n2)
          acc[m][n2] = __builtin_amdgcn_mfma_f32_16x16x32_bf16(af[m], bfv[n2], acc[m][n2], 0, 0, 0);
    }
  }

  const int ho = blockIdx.y * 4 + wv;
  #pragma unroll
  for (int m = 0; m < 2; ++m) {
    #pragma unroll
    for (int n2 = 0; n2 < 4; ++n2) {
      int co = n2 * 16 + (lane & 15);
      float bb = bias[co];
      #pragma unroll
      for (int qh = 0; qh < 2; ++qh) {
        int qq = 2 * qh;
        float v0 = fmaxf(acc[m][n2][qq] + bb, 0.f);
        float v1 = fmaxf(acc[m][n2][qq + 1] + bb, 0.f);
        float v2 = fmaxf(acc[m + 2][n2][qq] + bb, 0.f);
        float v3 = fmaxf(acc[m + 2][n2][qq + 1] + bb, 0.f);
        float mx = fmaxf(fmaxf(v0, v1), fmaxf(v2, v3));
        int wl = (m * 16 + ((lane >> 4) << 2) + qq) & 31;
        int wo = (w0 >> 1) + (wl >> 1);
        out[(((long)n * 112 + ho) * 112 + wo) * 64 + co] = __float2bfloat16(mx);
      }
    }
  }
}

// ---------------------------------------------------------------- conv_halo1: L1 (conv2: 64->128, 112x112, no pool)
__global__ __launch_bounds__(512) void conv_halo1(
    const bf16* __restrict__ in, const bf16* __restrict__ wp,
    const float* __restrict__ bias, bf16* __restrict__ out,
    const bf16* __restrict__ zp) {
  __shared__ bf16 tA[18 * 18 * 64];      // 41472 B; row stride 2304 B
  __shared__ bf16 tB[2][128 * 64];       // 2 x 16384 B
  const int tid = threadIdx.x;
  const int lane = tid & 63, wv = tid >> 6;
  const int wr = wv >> 1, wc = wv & 1;
  const int n = blockIdx.z;
  const int h0 = blockIdx.y * 16, w0 = blockIdx.x * 16;

  #pragma unroll
  for (int i = 0; i < 6; ++i) {
    int cid = i * 512 + tid;
    if (cid < 2592) {
      int row = cid / 144;
      int rem = cid - row * 144;
      int w = rem >> 3, j = rem & 7;
      int hg = h0 - 1 + row, wg = w0 - 1 + w;
      bool ok = (hg >= 0) & (hg < 112) & (wg >= 0) & (wg < 112);
      const bf16* src = ok ? (in + (((long)n * 112 + hg) * 112 + wg) * 64 + ((j ^ (w & 7)) << 3))
                           : zp;
      gl16(src, tA + (long)cid * 8);
    }
  }
  #pragma unroll
  for (int i = 0; i < 2; ++i) {
    int cid = i * 512 + tid;
    int co = cid >> 3, j = cid & 7;
    gl16(wp + (long)co * 576 + ((j ^ (co & 7)) << 3), tB[0] + (long)cid * 8);
  }
  __syncthreads();

  f32x4 acc[4][4];
  #pragma unroll
  for (int m = 0; m < 4; ++m)
    #pragma unroll
    for (int n2 = 0; n2 < 4; ++n2) acc[m][n2] = (f32x4){0.f, 0.f, 0.f, 0.f};

  for (int pos = 0; pos < 9; ++pos) {
    if (pos < 8) {
      bf16* dst = tB[(pos + 1) & 1];
      #pragma unroll
      for (int i = 0; i < 2; ++i) {
        int cid = i * 512 + tid;
        int co = cid >> 3, j = cid & 7;
        gl16(wp + (long)co * 576 + (pos + 1) * 64 + ((j ^ (co & 7)) << 3), dst + (long)cid * 8);
      }
    }
    const bf16* bB = tB[pos & 1];
    const int dh = pos / 3, dw = pos - (pos / 3) * 3;
    #pragma unroll
    for (int ks = 0; ks < 2; ++ks) {
      const int kb = ks * 64 + (lane >> 4) * 16;
      bf16x8 af[4], bfv[4];
      #pragma unroll
      for (int m = 0; m < 4; ++m) {
        int hl = wr * 4 + m + dh;
        int wl = (lane & 15) + dw;
        af[m] = *(const bf16x8*)((const char*)tA + hl * 2304 + wl * 128 + (kb ^ ((wl & 7) << 4)));
      }
      #pragma unroll
      for (int n2 = 0; n2 < 4; ++n2) {
        int c = wc * 64 + n2 * 16 + (lane & 15);
        bfv[n2] = *(const bf16x8*)((const char*)bB + c * 128 + (kb ^ ((c & 7) << 4)));
      }
      #pragma unroll
      for (int m = 0; m < 4; ++m)
        #pragma unroll
        for (int n2 = 0; n2 < 4; ++n2)
          acc[m][n2] = __builtin_amdgcn_mfma_f32_16x16x32_bf16(af[m], bfv[n2], acc[m][n2], 0, 0, 0);
    }
    __syncthreads();
  }

  #pragma unroll
  for (int m = 0; m < 4; ++m) {
    const int h = h0 + wr * 4 + m;
    #pragma unroll
    for (int n2 = 0; n2 < 4; ++n2) {
      int co = wc * 64 + n2 * 16 + (lane & 15);
      float bb = bias[co];
      #pragma unroll
      for (int qq = 0; qq < 4; ++qq) {
        int w = w0 + (lane >> 4) * 4 + qq;
        out[(((long)n * 112 + h) * 112 + w) * 128 + co] =
            __float2bfloat16(fmaxf(acc[m][n2][qq] + bb, 0.f));
      }
    }
  }
}

// ---------------------------------------------------------------- conv_halo128p: L[2] (conv4: 128->128, 112x112) + FUSED pool2
__global__ __launch_bounds__(512) void conv_halo128p(
    const bf16* __restrict__ in, const bf16* __restrict__ wp,
    const float* __restrict__ bias, bf16* __restrict__ out,
    const bf16* __restrict__ zp) {
  __shared__ bf16 tA[18 * 18 * 128];     // 82944 B; point stride 256 B, row stride 4608 B
  __shared__ bf16 tB[2][128 * 128];      // 2 x 32768 B
  const int tid = threadIdx.x;
  const int lane = tid & 63, wv = tid >> 6;
  const int wr = wv >> 1, wc = wv & 1;   // 4 p-groups x 2 co-groups
  const int n = blockIdx.z;
  const int h0 = blockIdx.y * 16, w0 = blockIdx.x * 16;

  #pragma unroll
  for (int i = 0; i < 11; ++i) {
    int cid = i * 512 + tid;
    if (cid < 5184) {
      int row = cid / 288;
      int rem = cid - row * 288;
      int w = rem >> 4, j = rem & 15;
      int hg = h0 - 1 + row, wg = w0 - 1 + w;
      bool ok = (hg >= 0) & (hg < 112) & (wg >= 0) & (wg < 112);
      const bf16* src = ok ? (in + (((long)n * 112 + hg) * 112 + wg) * 128 + ((j ^ (w & 7)) << 3))
                           : zp;
      gl16(src, tA + (long)cid * 8);
    }
  }
  #pragma unroll
  for (int i = 0; i < 4; ++i) {
    int cid = i * 512 + tid;
    int co = cid >> 4, j = cid & 15;
    const bf16* src = wp + (long)co * 1152 + ((j ^ (co & 7)) << 3);
    gl16(src, tB[0] + (long)cid * 8);
  }
  __syncthreads();

  f32x4 acc[4][4];
  #pragma unroll
  for (int m = 0; m < 4; ++m)
    #pragma unroll
    for (int n2 = 0; n2 < 4; ++n2) acc[m][n2] = (f32x4){0.f, 0.f, 0.f, 0.f};

  for (int pos = 0; pos < 9; ++pos) {
    if (pos < 8) {
      bf16* dst = tB[(pos + 1) & 1];
      #pragma unroll
      for (int i = 0; i < 4; ++i) {
        int cid = i * 512 + tid;
        int co = cid >> 4, j = cid & 15;
        const bf16* src = wp + (long)co * 1152 + (pos + 1) * 128 + ((j ^ (co & 7)) << 3);
        gl16(src, dst + (long)cid * 8);
      }
    }
    const bf16* bB = tB[pos & 1];
    const int dh = pos / 3, dw = pos - (pos / 3) * 3;
    #pragma unroll
    for (int kq = 0; kq < 4; ++kq) {
      const int kb = kq * 64 + (lane >> 4) * 16;
      bf16x8 af[4], bfv[4];
      #pragma unroll
      for (int m = 0; m < 4; ++m) {
        int hl = wr * 4 + m + dh;
        int wl = (lane & 15) + dw;
        af[m] = *(const bf16x8*)((const char*)tA + hl * 4608 + wl * 256 + (kb ^ ((wl & 7) << 4)));
      }
      #pragma unroll
      for (int n2 = 0; n2 < 4; ++n2) {
        int c = wc * 64 + n2 * 16 + (lane & 15);
        bfv[n2] = *(const bf16x8*)((const char*)bB + c * 256 + (kb ^ ((c & 7) << 4)));
      }
      #pragma unroll
      for (int m = 0; m < 4; ++m)
        #pragma unroll
        for (int n2 = 0; n2 < 4; ++n2)
          acc[m][n2] = __builtin_amdgcn_mfma_f32_16x16x32_bf16(af[m], bfv[n2], acc[m][n2], 0, 0, 0);
    }
    __syncthreads();
  }

  const int hoB = blockIdx.y * 8, woB = blockIdx.x * 8;
  #pragma unroll
  for (int mh = 0; mh < 2; ++mh) {
    const int m = 2 * mh;
    const int ho = hoB + wr * 2 + mh;
    #pragma unroll
    for (int n2 = 0; n2 < 4; ++n2) {
      int co = wc * 64 + n2 * 16 + (lane & 15);
      float bb = bias[co];
      #pragma unroll
      for (int qh = 0; qh < 2; ++qh) {
        int qq = 2 * qh;
        float v0 = fmaxf(acc[m][n2][qq] + bb, 0.f);
        float v1 = fmaxf(acc[m][n2][qq + 1] + bb, 0.f);
        float v2 = fmaxf(acc[m + 1][n2][qq] + bb, 0.f);
        float v3 = fmaxf(acc[m + 1][n2][qq + 1] + bb, 0.f);
        float mx = fmaxf(fmaxf(v0, v1), fmaxf(v2, v3));
        int wo = woB + (lane >> 4) * 2 + qh;
        out[(((long)n * 56 + ho) * 56 + wo) * 128 + co] = __float2bfloat16(mx);
      }
    }
  }
}

// ---------------------------------------------------------------- implicit-GEMM conv (NHWC, bf16 MFMA 16x16x32)
template <int BM, int BN, int WM, int WN, int SPLITK>
__global__ __launch_bounds__(WM* WN * 64) void conv_gemm(
    const bf16* __restrict__ in, const bf16* __restrict__ wp,
    const float* __restrict__ bias, bf16* __restrict__ out,
    float* __restrict__ pout, const bf16* __restrict__ zp,
    int Cin, int cshift, int Cout, int H, int W, int NHW) {
  constexpr int NT = WM * WN * 64;
  constexpr int IA = BM * 8 / NT;
  constexpr int IB = BN * 8 / NT;
  __shared__ bf16 lA[BM * 64];
  __shared__ bf16 lB[BN * 64];
  const int tid = threadIdx.x;
  const int lane = tid & 63, wv = tid >> 6;
  const int wr = wv / WN, wc = wv % WN;

  const int gx = gridDim.x;
  const int nwg = gx * gridDim.y;
  const int fid = blockIdx.y * gx + blockIdx.x;
  const int q = nwg >> 3, r = nwg & 7;
  const int xcd = fid & 7, idx = fid >> 3;
  const int swz = (xcd < r ? xcd * (q + 1) : r * (q + 1) + (xcd - r) * q) + idx;
  const int p0 = (swz % gx) * BM;
  const int co0 = (swz / gx) * BN;

  const int K = 9 << cshift;
  const int HW = H * W;
  const int colx = ((tid & 7) ^ ((tid >> 3) & 7)) * 8;

  int baseA[IA]; short hA[IA], wA[IA];
  #pragma unroll
  for (int i = 0; i < IA; ++i) {
    int rr = i * (NT / 8) + (tid >> 3);
    int p = p0 + rr;
    if (p < NHW) {
      int n = p / HW; int rem = p - n * HW; int h = rem / W; int w_ = rem - h * W;
      hA[i] = (short)h; wA[i] = (short)w_;
      baseA[i] = ((n * H + h) * W + w_) * Cin;
    } else { hA[i] = -9999; wA[i] = -9999; baseA[i] = 0; }
  }

  f32x4 acc[4][4];
  #pragma unroll
  for (int m = 0; m < 4; ++m)
    #pragma unroll
    for (int n2 = 0; n2 < 4; ++n2) acc[m][n2] = (f32x4){0.f, 0.f, 0.f, 0.f};

  const int Kper = K / SPLITK;
  const int kBeg = (SPLITK > 1) ? (int)blockIdx.z * Kper : 0;
  const int kEnd = kBeg + Kper;

  const bf16* srcB[IB];
  #pragma unroll
  for (int i = 0; i < IB; ++i) {
    int col = i * (NT / 8) + (tid >> 3);
    srcB[i] = wp + (long)(co0 + col) * K + kBeg + colx;
  }

  int kk = kBeg;
  while (kk < kEnd) {
    const int pos = kk >> cshift;
    const int dh = pos / 3 - 1, dw = pos - (pos / 3) * 3 - 1;
    int posEnd = (pos + 1) << cshift;
    if (posEnd > kEnd) posEnd = kEnd;
    const bf16* srcA[IA];
    {
      const int doff = (dh * W + dw) * Cin + (kk & (Cin - 1)) + colx;
      #pragma unroll
      for (int i = 0; i < IA; ++i) {
        int hh = hA[i] + dh, ww = wA[i] + dw;
        bool ok = (hh >= 0) & (hh < H) & (ww >= 0) & (ww < W);
        srcA[i] = ok ? (in + baseA[i] + doff) : (zp + colx);
      }
    }
    for (; kk < posEnd; kk += 64) {
      __syncthreads();
      #pragma unroll
      for (int i = 0; i < IA; ++i) {
        gl16(srcA[i], lA + i * (NT * 8) + wv * 512);
        srcA[i] += 64;
      }
      #pragma unroll
      for (int i = 0; i < IB; ++i) {
        gl16(srcB[i], lB + i * (NT * 8) + wv * 512);
        srcB[i] += 64;
      }
      __syncthreads();
      #pragma unroll
      for (int ks = 0; ks < 2; ++ks) {
        const int kb = ks * 64 + (lane >> 4) * 16;
        bf16x8 af[4], bfv[4];
        #pragma unroll
        for (int m = 0; m < 4; ++m) {
          int rr = wr * 64 + m * 16 + (lane & 15);
          af[m] = *(const bf16x8*)((const char*)lA + rr * 128 + (kb ^ ((rr & 7) << 4)));
        }
        #pragma unroll
        for (int n2 = 0; n2 < 4; ++n2) {
          int c = wc * 64 + n2 * 16 + (lane & 15);
          bfv[n2] = *(const bf16x8*)((const char*)lB + c * 128 + (kb ^ ((c & 7) << 4)));
        }
        #pragma unroll
        for (int m = 0; m < 4; ++m)
          #pragma unroll
          for (int n2 = 0; n2 < 4; ++n2)
            acc[m][n2] = __builtin_amdgcn_mfma_f32_16x16x32_bf16(af[m], bfv[n2], acc[m][n2], 0, 0, 0);
      }
    }
  }

  if constexpr (SPLITK == 1) {
    #pragma unroll
    for (int m = 0; m < 4; ++m) {
      int pb = p0 + wr * 64 + m * 16 + (lane >> 4) * 4;
      #pragma unroll
      for (int n2 = 0; n2 < 4; ++n2) {
        int co = co0 + wc * 64 + n2 * 16 + (lane & 15);
        float bb = bias[co];
        #pragma unroll
        for (int qq = 0; qq < 4; ++qq) {
          int pp = pb + qq;
          if (pp < NHW)
            out[(long)pp * Cout + co] = __float2bfloat16(fmaxf(acc[m][n2][qq] + bb, 0.f));
        }
      }
    }
  } else {
    float* pb_ = pout + (long)blockIdx.z * NHW * Cout;
    #pragma unroll
    for (int m = 0; m < 4; ++m) {
      int pb = p0 + wr * 64 + m * 16 + (lane >> 4) * 4;
      #pragma unroll
      for (int n2 = 0; n2 < 4; ++n2) {
        int co = co0 + wc * 64 + n2 * 16 + (lane & 15);
        #pragma unroll
        for (int qq = 0; qq < 4; ++qq) {
          int pp = pb + qq;
          if (pp < NHW) pb_[(long)pp * Cout + co] = acc[m][n2][qq];
        }
      }
    }
  }
}

// ---------------------------------------------------------------- split-K reduce (+bias+relu+bf16), optionally fused 2x2 maxpool
template <int NPARTS, bool POOL>
__global__ __launch_bounds__(256) void reduce_split(
    const float* __restrict__ part, const float* __restrict__ bias,
    bf16* __restrict__ out, int NHW, int H, int W, int C) {
  const long total = (long)NHW * C;
  if constexpr (!POOL) {
    long e4 = ((long)blockIdx.x * 256 + threadIdx.x) * 4;
    if (e4 >= total) return;
    f32x4 s = *(const f32x4*)(part + e4);
    #pragma unroll
    for (int p2 = 1; p2 < NPARTS; ++p2) {
      f32x4 b = *(const f32x4*)(part + (long)p2 * total + e4);
      s += b;
    }
    f32x4 bv = *(const f32x4*)(bias + (int)(e4 & (C - 1)));
    s16x4 r;
    #pragma unroll
    for (int u = 0; u < 4; ++u) r[u] = f2s(fmaxf(s[u] + bv[u], 0.f));
    *(s16x4*)(out + e4) = r;
  } else {
    const int H2 = H >> 1, W2 = W >> 1;
    long id4 = ((long)blockIdx.x * 256 + threadIdx.x) * 4;
    long ptotal = ((long)NHW / 4) * C;
    if (id4 >= ptotal) return;
    int c4 = (int)(id4 & (C - 1));
    long rest = id4 / C;
    int wo = (int)(rest % W2);
    long t2 = rest / W2;
    int ho = (int)(t2 % H2);
    int n = (int)(t2 / H2);
    f32x4 bv = *(const f32x4*)(bias + c4);
    f32x4 mx;
    #pragma unroll
    for (int dy = 0; dy < 2; ++dy)
      #pragma unroll
      for (int dx = 0; dx < 2; ++dx) {
        long p = ((long)n * H + 2 * ho + dy) * W + 2 * wo + dx;
        long e = p * C + c4;
        f32x4 s = *(const f32x4*)(part + e);
        #pragma unroll
        for (int p2 = 1; p2 < NPARTS; ++p2) {
          f32x4 b = *(const f32x4*)(part + (long)p2 * total + e);
          s += b;
        }
        s += bv;
        if (dy == 0 && dx == 0) mx = s;
        else {
          #pragma unroll
          for (int u = 0; u < 4; ++u) mx[u] = fmaxf(mx[u], s[u]);
        }
      }
    s16x4 r;
    #pragma unroll
    for (int u = 0; u < 4; ++u) r[u] = f2s(fmaxf(mx[u], 0.f));
    *(s16x4*)(out + ((long)(n * H2 + ho) * W2 + wo) * C + c4) = r;
  }
}

// ---------------------------------------------------------------- maxpool 2x2 NHWC (short8 vectors)
__global__ void maxpool_nhwc(const bf16* __restrict__ in, bf16* __restrict__ out,
                             int H, int W, int C, int cshift3, int WC8) {
  const int id = blockIdx.x * 256 + threadIdx.x;
  if (id >= WC8) return;
  const int H2 = H >> 1, W2 = W >> 1;
  const int ho = blockIdx.y, n = blockIdx.z;
  const int wo = id >> cshift3, c8 = id & ((1 << cshift3) - 1);
  const bf16* p = in + (((long)(n * H + 2 * ho) * W) + 2 * wo) * C + c8 * 8;
  short8 a = *(const short8*)p;
  short8 bq = *(const short8*)(p + C);
  short8 c = *(const short8*)(p + (long)W * C);
  short8 d = *(const short8*)(p + (long)W * C + C);
  short8 r;
  #pragma unroll
  for (int u = 0; u < 8; ++u) {
    float m = fmaxf(fmaxf(s2f(a[u]), s2f(bq[u])), fmaxf(s2f(c[u]), s2f(d[u])));
    r[u] = f2s(m);
  }
  *(short8*)(out + ((long)(n * H2 + ho) * W2 + wo) * C + c8 * 8) = r;
}

// ---------------------------------------------------------------- FC1 partial (kPer=128, 784 blocks)
__global__ __launch_bounds__(256) void fc1_partial(
    const bf16* __restrict__ in, const float* __restrict__ w,
    float* __restrict__ part) {
  const int j0 = blockIdx.x * 1024 + threadIdx.x * 4;
  const int k0 = blockIdx.y * 128;
  __shared__ float ilds[128][16];
  #pragma unroll
  for (int i = 0; i < 8; ++i) {
    int e = i * 256 + threadIdx.x;
    int kk = e >> 4, n = e & 15;
    int k = k0 + kk;
    int cch = k / 49, s = k - cch * 49;
    ilds[kk][n] = s2f(__builtin_bit_cast(short, in[((long)n * 49 + s) * 512 + cch]));
  }
  __syncthreads();
  f32x4 acc[16];
  #pragma unroll
  for (int n = 0; n < 16; ++n) acc[n] = (f32x4){0.f, 0.f, 0.f, 0.f};
  #pragma unroll 4
  for (int kk = 0; kk < 128; ++kk) {
    f32x4 w4 = *(const f32x4*)(w + (long)(k0 + kk) * 4096 + j0);
    #pragma unroll
    for (int n = 0; n < 16; ++n) {
      float v = ilds[kk][n];
      acc[n] += v * w4;
    }
  }
  float* pp = part + (long)blockIdx.y * 16 * 4096;
  #pragma unroll
  for (int n = 0; n < 16; ++n) *(f32x4*)(pp + n * 4096 + j0) = acc[n];
}

// ---------------------------------------------------------------- FC2/FC3 partial (fp32 in, relu-on-read)
template <int KPER>
__global__ __launch_bounds__(256) void fc23_partial(
    const float* __restrict__ in, const float* __restrict__ w,
    float* __restrict__ part, int fin, int fout) {
  const int j0 = blockIdx.x * 1024 + threadIdx.x * 4;
  const int k0 = blockIdx.y * KPER;
  __shared__ float ilds[KPER][16];
  #pragma unroll
  for (int i = 0; i < KPER / 16; ++i) {
    int e = i * 256 + threadIdx.x;
    int kk = e >> 4, n = e & 15;
    ilds[kk][n] = fmaxf(in[(long)n * fin + k0 + kk], 0.f);
  }
  __syncthreads();
  if (j0 >= fout) return;
  f32x4 acc[16];
  #pragma unroll
  for (int n = 0; n < 16; ++n) acc[n] = (f32x4){0.f, 0.f, 0.f, 0.f};
  #pragma unroll 4
  for (int kk = 0; kk < KPER; ++kk) {
    f32x4 w4 = *(const f32x4*)(w + (long)(k0 + kk) * fout + j0);
    #pragma unroll
    for (int n = 0; n < 16; ++n) {
      float v = ilds[kk][n];
      acc[n] += v * w4;
    }
  }
  float* pp = part + (long)blockIdx.y * 16 * fout;
  #pragma unroll
  for (int n = 0; n < 16; ++n) *(f32x4*)(pp + n * fout + j0) = acc[n];
}

// ---------------------------------------------------------------- reduce FC partials + bias
__global__ void reduce_fc(const float* __restrict__ part, const float* __restrict__ bias,
                          float* __restrict__ out, int nparts, int fout, int total) {
  int i = blockIdx.x * 256 + threadIdx.x;
  if (i >= total) return;
  int n = i / fout, j = i - n * fout;
  float s = bias[j];
  for (int p = 0; p < nparts; ++p) s += part[((long)p * 16 + n) * fout + j];
  out[i] = s;
}

// ---------------------------------------------------------------- launch
extern "C" void kernel_launch(void* const* d_in, const int* in_sizes, int n_in,
                              void* d_out, int out_size, void* d_ws, size_t ws_size,
                              hipStream_t stream) {
  const float* x = (const float*)d_in[0];
  const float* cw[13]; const float* cb[13];
  for (int i = 0; i < 13; ++i) { cw[i] = (const float*)d_in[1 + 2 * i]; cb[i] = (const float*)d_in[2 + 2 * i]; }
  const float* fw1 = (const float*)d_in[27]; const float* fb1 = (const float*)d_in[28];
  const float* fw2 = (const float*)d_in[29]; const float* fb2 = (const float*)d_in[30];
  const float* fw3 = (const float*)d_in[31]; const float* fb3 = (const float*)d_in[32];
  float* outp = (float*)d_out;

  const size_t REGION = 102760448;  // 51,380,224 bf16 elems
  char* wsb = (char*)d_ws;
  bf16* A = (bf16*)wsb;
  bf16* B = (bf16*)(wsb + REGION);
  char* ST = wsb + 2 * REGION;
  bf16* zp = (bf16*)ST;                          // 4 KB zero page
  bf16* WBLOB = (bf16*)(ST + 4096);              // ~29.4 MB repacked weights
  char* ST2 = ST + 4096 + 31 * 1024 * 1024;
  float* F1 = (float*)ST2;                       // 16x4096 fp32
  float* F2 = F1 + 16 * 4096;
  float* PS = F2 + 16 * 4096;                    // split-K partials

  struct LayerCfg { int cin, cs, cout, H, W; };
  const LayerCfg L[12] = {
      {64, 6, 64, 224, 224},  {64, 6, 128, 112, 112}, {128, 7, 128, 112, 112},
      {128, 7, 256, 56, 56},  {256, 8, 256, 56, 56},  {256, 8, 256, 56, 56},
      {256, 8, 512, 28, 28},  {512, 9, 512, 28, 28},  {512, 9, 512, 28, 28},
      {512, 9, 512, 14, 14},  {512, 9, 512, 14, 14},  {512, 9, 512, 14, 14}};
  const bool poolAfter[12] = {true, false, true, false, false, true, false, false, true, false, false, true};

  RepackMeta rm;
  long off = 0;
  long offs[12];
  for (int li = 0; li < 12; ++li) {
    rm.src[li] = cw[li + 1];
    rm.cinM1[li] = L[li].cin - 1;
    rm.cshift[li] = L[li].cs;
    rm.cout[li] = L[li].cout;
    rm.dstOff[li] = off;
    offs[li] = off;
    off += (long)L[li].cout * (9 << L[li].cs);
  }
  zerofill<<<4, 256, 0, stream>>>((float*)zp, 1024);
  repack_all<<<dim3(512, 12), 256, 0, stream>>>(rm, WBLOB);

  conv1_first<<<dim3(14, 14, 16), 256, 0, stream>>>(x, cw[0], cb[0], A);

  bf16* cur = A;
  bf16* oth = B;
  for (int li = 0; li < 12; ++li) {
    const LayerCfg& c = L[li];
    bf16* wb = WBLOB + offs[li];
    const int NHW = 16 * c.H * c.W;
    const bool fusedPool = poolAfter[li] && (li == 0 || li == 2 || li >= 6);
    if (li == 0) {
      // 224x224, Cin=Cout=64: spatial-halo kernel with FUSED pool1 (writes 112x112x64)
      conv_halo64<<<dim3(7, 28, 16), 256, 0, stream>>>(cur, wb, cb[li + 1], oth, zp);
    } else if (li == 1) {
      // 112x112, 64->128: spatial-halo kernel (A staged once)
      conv_halo1<<<dim3(7, 7, 16), 512, 0, stream>>>(cur, wb, cb[li + 1], oth, zp);
    } else if (li == 2) {
      // 112x112, 128->128: spatial-halo kernel with FUSED pool2 (writes 56x56x128)
      conv_halo128p<<<dim3(7, 7, 16), 512, 0, stream>>>(cur, wb, cb[li + 1], oth, zp);
    } else if (li <= 5) {
      // 56x56: 8-wave tall-M tile <256,128> -> B staging halved vs <128,256>
      conv_gemm<256, 128, 4, 2, 1><<<dim3(NHW / 256, c.cout / 128), 512, 0, stream>>>(
          cur, wb, cb[li + 1], oth, nullptr, zp, c.cin, c.cs, c.cout, c.H, c.W, NHW);
    } else if (li <= 8) {
      // 28x28, N=512: split-K=2, 8-wave tall-M tile (49x4x2 = 392 WGs, B halved)
      conv_gemm<256, 128, 4, 2, 2><<<dim3(NHW / 256, c.cout / 128, 2), 512, 0, stream>>>(
          cur, wb, cb[li + 1], nullptr, PS, zp, c.cin, c.cs, c.cout, c.H, c.W, NHW);
      if (fusedPool) {
        long pt = ((long)NHW / 4) * c.cout;
        reduce_split<2, true><<<(int)((pt / 4 + 255) / 256), 256, 0, stream>>>(
            PS, cb[li + 1], oth, NHW, c.H, c.W, c.cout);
      } else {
        long tot = (long)NHW * c.cout;
        reduce_split<2, false><<<(int)((tot / 4 + 255) / 256), 256, 0, stream>>>(
            PS, cb[li + 1], oth, NHW, c.H, c.W, c.cout);
      }
    } else {
      // 14x14, N=512: split-K=4 -> 400 WGs + reduce (fused pool on L11)
      conv_gemm<128, 128, 2, 2, 4><<<dim3((NHW + 127) / 128, c.cout / 128, 4), 256, 0, stream>>>(
          cur, wb, cb[li + 1], nullptr, PS, zp, c.cin, c.cs, c.cout, c.H, c.W, NHW);
      if (fusedPool) {
        long pt = ((long)NHW / 4) * c.cout;
        reduce_split<4, true><<<(int)((pt / 4 + 255) / 256), 256, 0, stream>>>(
            PS, cb[li + 1], oth, NHW, c.H, c.W, c.cout);
      } else {
        long tot = (long)NHW * c.cout;
        reduce_split<4, false><<<(int)((tot / 4 + 255) / 256), 256, 0, stream>>>(
            PS, cb[li + 1], oth, NHW, c.H, c.W, c.cout);
      }
    }
    bf16* t = cur; cur = oth; oth = t;
    if (poolAfter[li] && !fusedPool) {
      int cs3 = (c.cout == 64) ? 3 : (c.cout == 128) ? 4 : (c.cout == 256) ? 5 : 6;
      int W2 = c.W / 2, H2 = c.H / 2;
      int WC8 = W2 << cs3;
      maxpool_nhwc<<<dim3((WC8 + 255) / 256, H2, 16), 256, 0, stream>>>(cur, oth, c.H, c.W, c.cout, cs3, WC8);
      t = cur; cur = oth; oth = t;
    }
  }
  // cur = pool5 output [16,7,7,512] NHWC bf16.
  float* P1 = (float*)oth;                                 // 196*16*4096*4 = 51.4 MB
  float* P2 = (float*)((char*)oth + 52u * 1024 * 1024);    // 128*16*4096*4 = 33.6 MB
  float* P3 = (float*)((char*)oth + 89u * 1024 * 1024);    // 128*16*1000*4 =  8.2 MB

  fc1_partial<<<dim3(4, 196), 256, 0, stream>>>(cur, fw1, P1);
  reduce_fc<<<(16 * 4096 + 255) / 256, 256, 0, stream>>>(P1, fb1, F1, 196, 4096, 16 * 4096);
  fc23_partial<32><<<dim3(4, 128), 256, 0, stream>>>(F1, fw2, P2, 4096, 4096);
  reduce_fc<<<(16 * 4096 + 255) / 256, 256, 0, stream>>>(P2, fb2, F2, 128, 4096, 16 * 4096);
  fc23_partial<32><<<dim3(1, 128), 256, 0, stream>>>(F2, fw3, P3, 4096, 1000);
  reduce_fc<<<(16 * 1000 + 255) / 256, 256, 0, stream>>>(P3, fb3, outp, 128, 1000, 16 * 1000);
}

// Round 16
// 1011.928 us; speedup vs baseline: 1.0578x; 1.0578x over previous
//
#include <hip/hip_runtime.h>
#include <hip/hip_bf16.h>

typedef __hip_bfloat16 bf16;
typedef __attribute__((ext_vector_type(4))) short s16x4;
typedef __attribute__((ext_vector_type(8))) short short8;
typedef __attribute__((ext_vector_type(8))) __bf16 bf16x8;
typedef __attribute__((ext_vector_type(4))) float f32x4;

__device__ __forceinline__ float s2f(short s) {
  return __builtin_bit_cast(float, (unsigned)((unsigned short)s) << 16);
}
__device__ __forceinline__ short f2s(float f) {
  return __builtin_bit_cast(short, __float2bfloat16(f));
}

__device__ __forceinline__ void gl16(const bf16* g, bf16* l) {
  __builtin_amdgcn_global_load_lds(
      (const __attribute__((address_space(1))) void*)g,
      (__attribute__((address_space(3))) void*)l, 16, 0, 0);
}

// ---------------------------------------------------------------- zero fill (zpage)
__global__ void zerofill(float* p, int n) {
  int i = blockIdx.x * 256 + threadIdx.x;
  if (i < n) p[i] = 0.f;
}

// ---------------------------------------------------------------- layer 1: 3->64, fp32 NCHW in, bf16 NHWC out
__global__ __launch_bounds__(256) void conv1_first(
    const float* __restrict__ x, const float* __restrict__ w,
    const float* __restrict__ b, bf16* __restrict__ out) {
  __shared__ float it[3][18][18];
  __shared__ float wl2[27 * 64];
  __shared__ float bl[64];
  const int tid = threadIdx.x;
  const int n = blockIdx.z;
  const int h0 = blockIdx.y * 16, w0 = blockIdx.x * 16;
  for (int i = tid; i < 1728; i += 256) {
    int jj = i >> 6, co = i & 63;
    wl2[i] = w[co * 27 + jj];
  }
  if (tid < 64) bl[tid] = b[tid];
  for (int i = tid; i < 972; i += 256) {
    int ci = i / 324; int r = i - ci * 324; int ty = r / 18, tx = r - ty * 18;
    int hh = h0 - 1 + ty, ww = w0 - 1 + tx;
    float v = 0.f;
    if (hh >= 0 && hh < 224 && ww >= 0 && ww < 224)
      v = x[((long)n * 3 + ci) * 50176 + hh * 224 + ww];
    it[ci][ty][tx] = v;
  }
  __syncthreads();
  const int ty = tid >> 4, tx = tid & 15;
  long ob = (((long)n * 224 + h0 + ty) * 224 + (w0 + tx)) * 64;
  for (int cog = 0; cog < 4; ++cog) {
    f32x4 a4[4];
    #pragma unroll
    for (int q = 0; q < 4; ++q) a4[q] = *(const f32x4*)&bl[cog * 16 + q * 4];
    #pragma unroll
    for (int jj = 0; jj < 27; ++jj) {
      const int ci = jj / 9, r = jj - ci * 9, kh = r / 3, kw = r - kh * 3;
      float v = it[ci][ty + kh][tx + kw];
      const f32x4* wp4 = (const f32x4*)&wl2[jj * 64 + cog * 16];
      #pragma unroll
      for (int q = 0; q < 4; ++q) a4[q] += v * wp4[q];
    }
    short8 s0, s1;
    #pragma unroll
    for (int u = 0; u < 4; ++u) {
      s0[u] = f2s(fmaxf(a4[0][u], 0.f));
      s0[4 + u] = f2s(fmaxf(a4[1][u], 0.f));
      s1[u] = f2s(fmaxf(a4[2][u], 0.f));
      s1[4 + u] = f2s(fmaxf(a4[3][u], 0.f));
    }
    *(short8*)(out + ob + cog * 16) = s0;
    *(short8*)(out + ob + cog * 16 + 8) = s1;
  }
}

// ---------------------------------------------------------------- fused weight repack (all 12 MFMA conv layers)
struct RepackMeta {
  const float* src[12];
  long dstOff[12];
  int cinM1[12];
  int cshift[12];
  int cout[12];
};

__global__ __launch_bounds__(256) void repack_all(RepackMeta m, bf16* __restrict__ blob) {
  const int li = blockIdx.y;
  const int co = blockIdx.x;
  if (co >= m.cout[li]) return;
  const int cs = m.cshift[li];
  const int cinM1 = m.cinM1[li];
  const int K = 9 << cs;
  const float* src = m.src[li] + (long)co * (cinM1 + 1) * 9;
  bf16* dst = blob + m.dstOff[li] + (long)co * K;
  for (int k = threadIdx.x; k < K; k += 256) {
    int pos = k >> cs;
    int ci = k & cinM1;
    dst[k] = __float2bfloat16(src[ci * 9 + pos]);
  }
}

// ---------------------------------------------------------------- conv_halo64: L0 (224x224, Cin=Cout=64) + FUSED 2x2 maxpool
__global__ __launch_bounds__(256) void conv_halo64(
    const bf16* __restrict__ in, const bf16* __restrict__ wp,
    const float* __restrict__ bias, bf16* __restrict__ out,
    const bf16* __restrict__ zp) {
  __shared__ bf16 tA[10 * 34 * 64];   // 43520 B; row stride 34*64=2176 elems (4352 B)
  __shared__ bf16 tB[9 * 64 * 64];    // 73728 B; 9 pos-blocks of [col][64]
  const int tid = threadIdx.x;
  const int lane = tid & 63, wv = tid >> 6;
  const int n = blockIdx.z;
  const int h0 = blockIdx.y * 8, w0 = blockIdx.x * 32;

  #pragma unroll
  for (int i = 0; i < 11; ++i) {
    int cid = i * 256 + tid;
    if (cid < 2720) {
      int row = cid / 272;
      int rem = cid - row * 272;
      int w = rem >> 3, j = rem & 7;
      int hg = h0 - 1 + row, wg = w0 - 1 + w;
      bool ok = (hg >= 0) & (hg < 224) & (wg >= 0) & (wg < 224);
      const bf16* src = ok ? (in + (((long)n * 224 + hg) * 224 + wg) * 64 + ((j ^ (w & 7)) << 3))
                           : zp;
      gl16(src, tA + (long)cid * 8);
    }
  }
  {
    const int colB = tid >> 3;
    const int colx = ((tid & 7) ^ (colB & 7)) * 8;
    const bf16* s0 = wp + (long)colB * 576 + colx;
    const bf16* s1 = wp + (long)(colB + 32) * 576 + colx;
    #pragma unroll
    for (int p = 0; p < 9; ++p) {
      gl16(s0 + p * 64, tB + p * 4096 + tid * 8);
      gl16(s1 + p * 64, tB + p * 4096 + 2048 + tid * 8);
    }
  }
  __syncthreads();

  f32x4 acc[4][4];
  #pragma unroll
  for (int m = 0; m < 4; ++m)
    #pragma unroll
    for (int n2 = 0; n2 < 4; ++n2) acc[m][n2] = (f32x4){0.f, 0.f, 0.f, 0.f};

  for (int pos = 0; pos < 9; ++pos) {
    const int dh = pos / 3, dw = pos - (pos / 3) * 3;
    #pragma unroll
    for (int ks = 0; ks < 2; ++ks) {
      const int kb = ks * 64 + (lane >> 4) * 16;
      bf16x8 af[4], bfv[4];
      #pragma unroll
      for (int m = 0; m < 4; ++m) {
        int p = wv * 64 + m * 16 + (lane & 15);
        int hl = (p >> 5) + dh, wl = (p & 31) + dw;
        af[m] = *(const bf16x8*)((const char*)tA + hl * 4352 + wl * 128 + (kb ^ ((wl & 7) << 4)));
      }
      #pragma unroll
      for (int n2 = 0; n2 < 4; ++n2) {
        int c = n2 * 16 + (lane & 15);
        bfv[n2] = *(const bf16x8*)((const char*)tB + pos * 8192 + c * 128 + (kb ^ ((c & 7) << 4)));
      }
      #pragma unroll
      for (int m = 0; m < 4; ++m)
        #pragma unroll
        for (int n2 = 0; n2 < 4; ++n2)
          acc[m][n2] = __builtin_amdgcn_mfma_f32_16x16x32_bf16(af[m], bfv[n2], acc[m][n2], 0, 0, 0);
    }
  }

  const int ho = blockIdx.y * 4 + wv;
  #pragma unroll
  for (int m = 0; m < 2; ++m) {
    #pragma unroll
    for (int n2 = 0; n2 < 4; ++n2) {
      int co = n2 * 16 + (lane & 15);
      float bb = bias[co];
      #pragma unroll
      for (int qh = 0; qh < 2; ++qh) {
        int qq = 2 * qh;
        float v0 = fmaxf(acc[m][n2][qq] + bb, 0.f);
        float v1 = fmaxf(acc[m][n2][qq + 1] + bb, 0.f);
        float v2 = fmaxf(acc[m + 2][n2][qq] + bb, 0.f);
        float v3 = fmaxf(acc[m + 2][n2][qq + 1] + bb, 0.f);
        float mx = fmaxf(fmaxf(v0, v1), fmaxf(v2, v3));
        int wl = (m * 16 + ((lane >> 4) << 2) + qq) & 31;
        int wo = (w0 >> 1) + (wl >> 1);
        out[(((long)n * 112 + ho) * 112 + wo) * 64 + co] = __float2bfloat16(mx);
      }
    }
  }
}

// ---------------------------------------------------------------- conv_halo1: L1 (conv2: 64->128, 112x112, no pool)
__global__ __launch_bounds__(512) void conv_halo1(
    const bf16* __restrict__ in, const bf16* __restrict__ wp,
    const float* __restrict__ bias, bf16* __restrict__ out,
    const bf16* __restrict__ zp) {
  __shared__ bf16 tA[18 * 18 * 64];      // 41472 B; row stride 2304 B
  __shared__ bf16 tB[2][128 * 64];       // 2 x 16384 B
  const int tid = threadIdx.x;
  const int lane = tid & 63, wv = tid >> 6;
  const int wr = wv >> 1, wc = wv & 1;
  const int n = blockIdx.z;
  const int h0 = blockIdx.y * 16, w0 = blockIdx.x * 16;

  #pragma unroll
  for (int i = 0; i < 6; ++i) {
    int cid = i * 512 + tid;
    if (cid < 2592) {
      int row = cid / 144;
      int rem = cid - row * 144;
      int w = rem >> 3, j = rem & 7;
      int hg = h0 - 1 + row, wg = w0 - 1 + w;
      bool ok = (hg >= 0) & (hg < 112) & (wg >= 0) & (wg < 112);
      const bf16* src = ok ? (in + (((long)n * 112 + hg) * 112 + wg) * 64 + ((j ^ (w & 7)) << 3))
                           : zp;
      gl16(src, tA + (long)cid * 8);
    }
  }
  #pragma unroll
  for (int i = 0; i < 2; ++i) {
    int cid = i * 512 + tid;
    int co = cid >> 3, j = cid & 7;
    gl16(wp + (long)co * 576 + ((j ^ (co & 7)) << 3), tB[0] + (long)cid * 8);
  }
  __syncthreads();

  f32x4 acc[4][4];
  #pragma unroll
  for (int m = 0; m < 4; ++m)
    #pragma unroll
    for (int n2 = 0; n2 < 4; ++n2) acc[m][n2] = (f32x4){0.f, 0.f, 0.f, 0.f};

  for (int pos = 0; pos < 9; ++pos) {
    if (pos < 8) {
      bf16* dst = tB[(pos + 1) & 1];
      #pragma unroll
      for (int i = 0; i < 2; ++i) {
        int cid = i * 512 + tid;
        int co = cid >> 3, j = cid & 7;
        gl16(wp + (long)co * 576 + (pos + 1) * 64 + ((j ^ (co & 7)) << 3), dst + (long)cid * 8);
      }
    }
    const bf16* bB = tB[pos & 1];
    const int dh = pos / 3, dw = pos - (pos / 3) * 3;
    #pragma unroll
    for (int ks = 0; ks < 2; ++ks) {
      const int kb = ks * 64 + (lane >> 4) * 16;
      bf16x8 af[4], bfv[4];
      #pragma unroll
      for (int m = 0; m < 4; ++m) {
        int hl = wr * 4 + m + dh;
        int wl = (lane & 15) + dw;
        af[m] = *(const bf16x8*)((const char*)tA + hl * 2304 + wl * 128 + (kb ^ ((wl & 7) << 4)));
      }
      #pragma unroll
      for (int n2 = 0; n2 < 4; ++n2) {
        int c = wc * 64 + n2 * 16 + (lane & 15);
        bfv[n2] = *(const bf16x8*)((const char*)bB + c * 128 + (kb ^ ((c & 7) << 4)));
      }
      #pragma unroll
      for (int m = 0; m < 4; ++m)
        #pragma unroll
        for (int n2 = 0; n2 < 4; ++n2)
          acc[m][n2] = __builtin_amdgcn_mfma_f32_16x16x32_bf16(af[m], bfv[n2], acc[m][n2], 0, 0, 0);
    }
    __syncthreads();
  }

  #pragma unroll
  for (int m = 0; m < 4; ++m) {
    const int h = h0 + wr * 4 + m;
    #pragma unroll
    for (int n2 = 0; n2 < 4; ++n2) {
      int co = wc * 64 + n2 * 16 + (lane & 15);
      float bb = bias[co];
      #pragma unroll
      for (int qq = 0; qq < 4; ++qq) {
        int w = w0 + (lane >> 4) * 4 + qq;
        out[(((long)n * 112 + h) * 112 + w) * 128 + co] =
            __float2bfloat16(fmaxf(acc[m][n2][qq] + bb, 0.f));
      }
    }
  }
}

// ---------------------------------------------------------------- conv_halo128p: L[2] (conv4: 128->128, 112x112) + FUSED pool2
__global__ __launch_bounds__(512) void conv_halo128p(
    const bf16* __restrict__ in, const bf16* __restrict__ wp,
    const float* __restrict__ bias, bf16* __restrict__ out,
    const bf16* __restrict__ zp) {
  __shared__ bf16 tA[18 * 18 * 128];     // 82944 B; point stride 256 B, row stride 4608 B
  __shared__ bf16 tB[2][128 * 128];      // 2 x 32768 B
  const int tid = threadIdx.x;
  const int lane = tid & 63, wv = tid >> 6;
  const int wr = wv >> 1, wc = wv & 1;   // 4 p-groups x 2 co-groups
  const int n = blockIdx.z;
  const int h0 = blockIdx.y * 16, w0 = blockIdx.x * 16;

  #pragma unroll
  for (int i = 0; i < 11; ++i) {
    int cid = i * 512 + tid;
    if (cid < 5184) {
      int row = cid / 288;
      int rem = cid - row * 288;
      int w = rem >> 4, j = rem & 15;
      int hg = h0 - 1 + row, wg = w0 - 1 + w;
      bool ok = (hg >= 0) & (hg < 112) & (wg >= 0) & (wg < 112);
      const bf16* src = ok ? (in + (((long)n * 112 + hg) * 112 + wg) * 128 + ((j ^ (w & 7)) << 3))
                           : zp;
      gl16(src, tA + (long)cid * 8);
    }
  }
  #pragma unroll
  for (int i = 0; i < 4; ++i) {
    int cid = i * 512 + tid;
    int co = cid >> 4, j = cid & 15;
    const bf16* src = wp + (long)co * 1152 + ((j ^ (co & 7)) << 3);
    gl16(src, tB[0] + (long)cid * 8);
  }
  __syncthreads();

  f32x4 acc[4][4];
  #pragma unroll
  for (int m = 0; m < 4; ++m)
    #pragma unroll
    for (int n2 = 0; n2 < 4; ++n2) acc[m][n2] = (f32x4){0.f, 0.f, 0.f, 0.f};

  for (int pos = 0; pos < 9; ++pos) {
    if (pos < 8) {
      bf16* dst = tB[(pos + 1) & 1];
      #pragma unroll
      for (int i = 0; i < 4; ++i) {
        int cid = i * 512 + tid;
        int co = cid >> 4, j = cid & 15;
        const bf16* src = wp + (long)co * 1152 + (pos + 1) * 128 + ((j ^ (co & 7)) << 3);
        gl16(src, dst + (long)cid * 8);
      }
    }
    const bf16* bB = tB[pos & 1];
    const int dh = pos / 3, dw = pos - (pos / 3) * 3;
    #pragma unroll
    for (int kq = 0; kq < 4; ++kq) {
      const int kb = kq * 64 + (lane >> 4) * 16;
      bf16x8 af[4], bfv[4];
      #pragma unroll
      for (int m = 0; m < 4; ++m) {
        int hl = wr * 4 + m + dh;
        int wl = (lane & 15) + dw;
        af[m] = *(const bf16x8*)((const char*)tA + hl * 4608 + wl * 256 + (kb ^ ((wl & 7) << 4)));
      }
      #pragma unroll
      for (int n2 = 0; n2 < 4; ++n2) {
        int c = wc * 64 + n2 * 16 + (lane & 15);
        bfv[n2] = *(const bf16x8*)((const char*)bB + c * 256 + (kb ^ ((c & 7) << 4)));
      }
      #pragma unroll
      for (int m = 0; m < 4; ++m)
        #pragma unroll
        for (int n2 = 0; n2 < 4; ++n2)
          acc[m][n2] = __builtin_amdgcn_mfma_f32_16x16x32_bf16(af[m], bfv[n2], acc[m][n2], 0, 0, 0);
    }
    __syncthreads();
  }

  const int hoB = blockIdx.y * 8, woB = blockIdx.x * 8;
  #pragma unroll
  for (int mh = 0; mh < 2; ++mh) {
    const int m = 2 * mh;
    const int ho = hoB + wr * 2 + mh;
    #pragma unroll
    for (int n2 = 0; n2 < 4; ++n2) {
      int co = wc * 64 + n2 * 16 + (lane & 15);
      float bb = bias[co];
      #pragma unroll
      for (int qh = 0; qh < 2; ++qh) {
        int qq = 2 * qh;
        float v0 = fmaxf(acc[m][n2][qq] + bb, 0.f);
        float v1 = fmaxf(acc[m][n2][qq + 1] + bb, 0.f);
        float v2 = fmaxf(acc[m + 1][n2][qq] + bb, 0.f);
        float v3 = fmaxf(acc[m + 1][n2][qq + 1] + bb, 0.f);
        float mx = fmaxf(fmaxf(v0, v1), fmaxf(v2, v3));
        int wo = woB + (lane >> 4) * 2 + qh;
        out[(((long)n * 56 + ho) * 56 + wo) * 128 + co] = __float2bfloat16(mx);
      }
    }
  }
}

// ---------------------------------------------------------------- implicit-GEMM conv (NHWC, bf16 MFMA 16x16x32)
template <int BM, int BN, int WM, int WN, int SPLITK>
__global__ __launch_bounds__(WM* WN * 64) void conv_gemm(
    const bf16* __restrict__ in, const bf16* __restrict__ wp,
    const float* __restrict__ bias, bf16* __restrict__ out,
    float* __restrict__ pout, const bf16* __restrict__ zp,
    int Cin, int cshift, int Cout, int H, int W, int NHW) {
  constexpr int NT = WM * WN * 64;
  constexpr int IA = BM * 8 / NT;
  constexpr int IB = BN * 8 / NT;
  __shared__ bf16 lA[BM * 64];
  __shared__ bf16 lB[BN * 64];
  const int tid = threadIdx.x;
  const int lane = tid & 63, wv = tid >> 6;
  const int wr = wv / WN, wc = wv % WN;

  const int gx = gridDim.x;
  const int nwg = gx * gridDim.y;
  const int fid = blockIdx.y * gx + blockIdx.x;
  const int q = nwg >> 3, r = nwg & 7;
  const int xcd = fid & 7, idx = fid >> 3;
  const int swz = (xcd < r ? xcd * (q + 1) : r * (q + 1) + (xcd - r) * q) + idx;
  const int p0 = (swz % gx) * BM;
  const int co0 = (swz / gx) * BN;

  const int K = 9 << cshift;
  const int HW = H * W;
  const int colx = ((tid & 7) ^ ((tid >> 3) & 7)) * 8;

  int baseA[IA]; short hA[IA], wA[IA];
  #pragma unroll
  for (int i = 0; i < IA; ++i) {
    int rr = i * (NT / 8) + (tid >> 3);
    int p = p0 + rr;
    if (p < NHW) {
      int n = p / HW; int rem = p - n * HW; int h = rem / W; int w_ = rem - h * W;
      hA[i] = (short)h; wA[i] = (short)w_;
      baseA[i] = ((n * H + h) * W + w_) * Cin;
    } else { hA[i] = -9999; wA[i] = -9999; baseA[i] = 0; }
  }

  f32x4 acc[4][4];
  #pragma unroll
  for (int m = 0; m < 4; ++m)
    #pragma unroll
    for (int n2 = 0; n2 < 4; ++n2) acc[m][n2] = (f32x4){0.f, 0.f, 0.f, 0.f};

  const int Kper = K / SPLITK;
  const int kBeg = (SPLITK > 1) ? (int)blockIdx.z * Kper : 0;
  const int kEnd = kBeg + Kper;

  const bf16* srcB[IB];
  #pragma unroll
  for (int i = 0; i < IB; ++i) {
    int col = i * (NT / 8) + (tid >> 3);
    srcB[i] = wp + (long)(co0 + col) * K + kBeg + colx;
  }

  int kk = kBeg;
  while (kk < kEnd) {
    const int pos = kk >> cshift;
    const int dh = pos / 3 - 1, dw = pos - (pos / 3) * 3 - 1;
    int posEnd = (pos + 1) << cshift;
    if (posEnd > kEnd) posEnd = kEnd;
    const bf16* srcA[IA];
    {
      const int doff = (dh * W + dw) * Cin + (kk & (Cin - 1)) + colx;
      #pragma unroll
      for (int i = 0; i < IA; ++i) {
        int hh = hA[i] + dh, ww = wA[i] + dw;
        bool ok = (hh >= 0) & (hh < H) & (ww >= 0) & (ww < W);
        srcA[i] = ok ? (in + baseA[i] + doff) : (zp + colx);
      }
    }
    for (; kk < posEnd; kk += 64) {
      __syncthreads();
      #pragma unroll
      for (int i = 0; i < IA; ++i) {
        gl16(srcA[i], lA + i * (NT * 8) + wv * 512);
        srcA[i] += 64;
      }
      #pragma unroll
      for (int i = 0; i < IB; ++i) {
        gl16(srcB[i], lB + i * (NT * 8) + wv * 512);
        srcB[i] += 64;
      }
      __syncthreads();
      #pragma unroll
      for (int ks = 0; ks < 2; ++ks) {
        const int kb = ks * 64 + (lane >> 4) * 16;
        bf16x8 af[4], bfv[4];
        #pragma unroll
        for (int m = 0; m < 4; ++m) {
          int rr = wr * 64 + m * 16 + (lane & 15);
          af[m] = *(const bf16x8*)((const char*)lA + rr * 128 + (kb ^ ((rr & 7) << 4)));
        }
        #pragma unroll
        for (int n2 = 0; n2 < 4; ++n2) {
          int c = wc * 64 + n2 * 16 + (lane & 15);
          bfv[n2] = *(const bf16x8*)((const char*)lB + c * 128 + (kb ^ ((c & 7) << 4)));
        }
        #pragma unroll
        for (int m = 0; m < 4; ++m)
          #pragma unroll
          for (int n2 = 0; n2 < 4; ++n2)
            acc[m][n2] = __builtin_amdgcn_mfma_f32_16x16x32_bf16(af[m], bfv[n2], acc[m][n2], 0, 0, 0);
      }
    }
  }

  if constexpr (SPLITK == 1) {
    #pragma unroll
    for (int m = 0; m < 4; ++m) {
      int pb = p0 + wr * 64 + m * 16 + (lane >> 4) * 4;
      #pragma unroll
      for (int n2 = 0; n2 < 4; ++n2) {
        int co = co0 + wc * 64 + n2 * 16 + (lane & 15);
        float bb = bias[co];
        #pragma unroll
        for (int qq = 0; qq < 4; ++qq) {
          int pp = pb + qq;
          if (pp < NHW)
            out[(long)pp * Cout + co] = __float2bfloat16(fmaxf(acc[m][n2][qq] + bb, 0.f));
        }
      }
    }
  } else {
    float* pb_ = pout + (long)blockIdx.z * NHW * Cout;
    #pragma unroll
    for (int m = 0; m < 4; ++m) {
      int pb = p0 + wr * 64 + m * 16 + (lane >> 4) * 4;
      #pragma unroll
      for (int n2 = 0; n2 < 4; ++n2) {
        int co = co0 + wc * 64 + n2 * 16 + (lane & 15);
        #pragma unroll
        for (int qq = 0; qq < 4; ++qq) {
          int pp = pb + qq;
          if (pp < NHW) pb_[(long)pp * Cout + co] = acc[m][n2][qq];
        }
      }
    }
  }
}

// ---------------------------------------------------------------- split-K reduce (+bias+relu+bf16), optionally fused 2x2 maxpool
template <int NPARTS, bool POOL>
__global__ __launch_bounds__(256) void reduce_split(
    const float* __restrict__ part, const float* __restrict__ bias,
    bf16* __restrict__ out, int NHW, int H, int W, int C) {
  const long total = (long)NHW * C;
  if constexpr (!POOL) {
    long e4 = ((long)blockIdx.x * 256 + threadIdx.x) * 4;
    if (e4 >= total) return;
    f32x4 s = *(const f32x4*)(part + e4);
    #pragma unroll
    for (int p2 = 1; p2 < NPARTS; ++p2) {
      f32x4 b = *(const f32x4*)(part + (long)p2 * total + e4);
      s += b;
    }
    f32x4 bv = *(const f32x4*)(bias + (int)(e4 & (C - 1)));
    s16x4 r;
    #pragma unroll
    for (int u = 0; u < 4; ++u) r[u] = f2s(fmaxf(s[u] + bv[u], 0.f));
    *(s16x4*)(out + e4) = r;
  } else {
    const int H2 = H >> 1, W2 = W >> 1;
    long id4 = ((long)blockIdx.x * 256 + threadIdx.x) * 4;
    long ptotal = ((long)NHW / 4) * C;
    if (id4 >= ptotal) return;
    int c4 = (int)(id4 & (C - 1));
    long rest = id4 / C;
    int wo = (int)(rest % W2);
    long t2 = rest / W2;
    int ho = (int)(t2 % H2);
    int n = (int)(t2 / H2);
    f32x4 bv = *(const f32x4*)(bias + c4);
    f32x4 mx;
    #pragma unroll
    for (int dy = 0; dy < 2; ++dy)
      #pragma unroll
      for (int dx = 0; dx < 2; ++dx) {
        long p = ((long)n * H + 2 * ho + dy) * W + 2 * wo + dx;
        long e = p * C + c4;
        f32x4 s = *(const f32x4*)(part + e);
        #pragma unroll
        for (int p2 = 1; p2 < NPARTS; ++p2) {
          f32x4 b = *(const f32x4*)(part + (long)p2 * total + e);
          s += b;
        }
        s += bv;
        if (dy == 0 && dx == 0) mx = s;
        else {
          #pragma unroll
          for (int u = 0; u < 4; ++u) mx[u] = fmaxf(mx[u], s[u]);
        }
      }
    s16x4 r;
    #pragma unroll
    for (int u = 0; u < 4; ++u) r[u] = f2s(fmaxf(mx[u], 0.f));
    *(s16x4*)(out + ((long)(n * H2 + ho) * W2 + wo) * C + c4) = r;
  }
}

// ---------------------------------------------------------------- maxpool 2x2 NHWC (short8 vectors)
__global__ void maxpool_nhwc(const bf16* __restrict__ in, bf16* __restrict__ out,
                             int H, int W, int C, int cshift3, int WC8) {
  const int id = blockIdx.x * 256 + threadIdx.x;
  if (id >= WC8) return;
  const int H2 = H >> 1, W2 = W >> 1;
  const int ho = blockIdx.y, n = blockIdx.z;
  const int wo = id >> cshift3, c8 = id & ((1 << cshift3) - 1);
  const bf16* p = in + (((long)(n * H + 2 * ho) * W) + 2 * wo) * C + c8 * 8;
  short8 a = *(const short8*)p;
  short8 bq = *(const short8*)(p + C);
  short8 c = *(const short8*)(p + (long)W * C);
  short8 d = *(const short8*)(p + (long)W * C + C);
  short8 r;
  #pragma unroll
  for (int u = 0; u < 8; ++u) {
    float m = fmaxf(fmaxf(s2f(a[u]), s2f(bq[u])), fmaxf(s2f(c[u]), s2f(d[u])));
    r[u] = f2s(m);
  }
  *(short8*)(out + ((long)(n * H2 + ho) * W2 + wo) * C + c8 * 8) = r;
}

// ---------------------------------------------------------------- FC1 partial (kPer=128, 784 blocks)
__global__ __launch_bounds__(256) void fc1_partial(
    const bf16* __restrict__ in, const float* __restrict__ w,
    float* __restrict__ part) {
  const int j0 = blockIdx.x * 1024 + threadIdx.x * 4;
  const int k0 = blockIdx.y * 128;
  __shared__ float ilds[128][16];
  #pragma unroll
  for (int i = 0; i < 8; ++i) {
    int e = i * 256 + threadIdx.x;
    int kk = e >> 4, n = e & 15;
    int k = k0 + kk;
    int cch = k / 49, s = k - cch * 49;
    ilds[kk][n] = s2f(__builtin_bit_cast(short, in[((long)n * 49 + s) * 512 + cch]));
  }
  __syncthreads();
  f32x4 acc[16];
  #pragma unroll
  for (int n = 0; n < 16; ++n) acc[n] = (f32x4){0.f, 0.f, 0.f, 0.f};
  #pragma unroll 4
  for (int kk = 0; kk < 128; ++kk) {
    f32x4 w4 = *(const f32x4*)(w + (long)(k0 + kk) * 4096 + j0);
    #pragma unroll
    for (int n = 0; n < 16; ++n) {
      float v = ilds[kk][n];
      acc[n] += v * w4;
    }
  }
  float* pp = part + (long)blockIdx.y * 16 * 4096;
  #pragma unroll
  for (int n = 0; n < 16; ++n) *(f32x4*)(pp + n * 4096 + j0) = acc[n];
}

// ---------------------------------------------------------------- FC2/FC3 partial (fp32 in, relu-on-read)
template <int KPER>
__global__ __launch_bounds__(256) void fc23_partial(
    const float* __restrict__ in, const float* __restrict__ w,
    float* __restrict__ part, int fin, int fout) {
  const int j0 = blockIdx.x * 1024 + threadIdx.x * 4;
  const int k0 = blockIdx.y * KPER;
  __shared__ float ilds[KPER][16];
  #pragma unroll
  for (int i = 0; i < KPER / 16; ++i) {
    int e = i * 256 + threadIdx.x;
    int kk = e >> 4, n = e & 15;
    ilds[kk][n] = fmaxf(in[(long)n * fin + k0 + kk], 0.f);
  }
  __syncthreads();
  if (j0 >= fout) return;
  f32x4 acc[16];
  #pragma unroll
  for (int n = 0; n < 16; ++n) acc[n] = (f32x4){0.f, 0.f, 0.f, 0.f};
  #pragma unroll 4
  for (int kk = 0; kk < KPER; ++kk) {
    f32x4 w4 = *(const f32x4*)(w + (long)(k0 + kk) * fout + j0);
    #pragma unroll
    for (int n = 0; n < 16; ++n) {
      float v = ilds[kk][n];
      acc[n] += v * w4;
    }
  }
  float* pp = part + (long)blockIdx.y * 16 * fout;
  #pragma unroll
  for (int n = 0; n < 16; ++n) *(f32x4*)(pp + n * fout + j0) = acc[n];
}

// ---------------------------------------------------------------- reduce FC partials + bias
__global__ void reduce_fc(const float* __restrict__ part, const float* __restrict__ bias,
                          float* __restrict__ out, int nparts, int fout, int total) {
  int i = blockIdx.x * 256 + threadIdx.x;
  if (i >= total) return;
  int n = i / fout, j = i - n * fout;
  float s = bias[j];
  for (int p = 0; p < nparts; ++p) s += part[((long)p * 16 + n) * fout + j];
  out[i] = s;
}

// ---------------------------------------------------------------- launch
extern "C" void kernel_launch(void* const* d_in, const int* in_sizes, int n_in,
                              void* d_out, int out_size, void* d_ws, size_t ws_size,
                              hipStream_t stream) {
  const float* x = (const float*)d_in[0];
  const float* cw[13]; const float* cb[13];
  for (int i = 0; i < 13; ++i) { cw[i] = (const float*)d_in[1 + 2 * i]; cb[i] = (const float*)d_in[2 + 2 * i]; }
  const float* fw1 = (const float*)d_in[27]; const float* fb1 = (const float*)d_in[28];
  const float* fw2 = (const float*)d_in[29]; const float* fb2 = (const float*)d_in[30];
  const float* fw3 = (const float*)d_in[31]; const float* fb3 = (const float*)d_in[32];
  float* outp = (float*)d_out;

  const size_t REGION = 102760448;  // 51,380,224 bf16 elems
  char* wsb = (char*)d_ws;
  bf16* A = (bf16*)wsb;
  bf16* B = (bf16*)(wsb + REGION);
  char* ST = wsb + 2 * REGION;
  bf16* zp = (bf16*)ST;                          // 4 KB zero page
  bf16* WBLOB = (bf16*)(ST + 4096);              // ~29.4 MB repacked weights
  char* ST2 = ST + 4096 + 31 * 1024 * 1024;
  float* F1 = (float*)ST2;                       // 16x4096 fp32
  float* F2 = F1 + 16 * 4096;
  float* PS = F2 + 16 * 4096;                    // split-K partials

  struct LayerCfg { int cin, cs, cout, H, W; };
  const LayerCfg L[12] = {
      {64, 6, 64, 224, 224},  {64, 6, 128, 112, 112}, {128, 7, 128, 112, 112},
      {128, 7, 256, 56, 56},  {256, 8, 256, 56, 56},  {256, 8, 256, 56, 56},
      {256, 8, 512, 28, 28},  {512, 9, 512, 28, 28},  {512, 9, 512, 28, 28},
      {512, 9, 512, 14, 14},  {512, 9, 512, 14, 14},  {512, 9, 512, 14, 14}};
  const bool poolAfter[12] = {true, false, true, false, false, true, false, false, true, false, false, true};

  RepackMeta rm;
  long off = 0;
  long offs[12];
  for (int li = 0; li < 12; ++li) {
    rm.src[li] = cw[li + 1];
    rm.cinM1[li] = L[li].cin - 1;
    rm.cshift[li] = L[li].cs;
    rm.cout[li] = L[li].cout;
    rm.dstOff[li] = off;
    offs[li] = off;
    off += (long)L[li].cout * (9 << L[li].cs);
  }
  zerofill<<<4, 256, 0, stream>>>((float*)zp, 1024);
  repack_all<<<dim3(512, 12), 256, 0, stream>>>(rm, WBLOB);

  conv1_first<<<dim3(14, 14, 16), 256, 0, stream>>>(x, cw[0], cb[0], A);

  bf16* cur = A;
  bf16* oth = B;
  for (int li = 0; li < 12; ++li) {
    const LayerCfg& c = L[li];
    bf16* wb = WBLOB + offs[li];
    const int NHW = 16 * c.H * c.W;
    const bool fusedPool = poolAfter[li] && (li == 0 || li == 2 || li >= 6);
    if (li == 0) {
      // 224x224, Cin=Cout=64: spatial-halo kernel with FUSED pool1 (writes 112x112x64)
      conv_halo64<<<dim3(7, 28, 16), 256, 0, stream>>>(cur, wb, cb[li + 1], oth, zp);
    } else if (li == 1) {
      // 112x112, 64->128: spatial-halo kernel (A staged once)
      conv_halo1<<<dim3(7, 7, 16), 512, 0, stream>>>(cur, wb, cb[li + 1], oth, zp);
    } else if (li == 2) {
      // 112x112, 128->128: spatial-halo kernel with FUSED pool2 (writes 56x56x128)
      conv_halo128p<<<dim3(7, 7, 16), 512, 0, stream>>>(cur, wb, cb[li + 1], oth, zp);
    } else if (li <= 5) {
      // 56x56, N=256: 392 WGs, 8-wave wide-N tile (REVERT to best-measured)
      conv_gemm<128, 256, 2, 4, 1><<<dim3(NHW / 128, 1), 512, 0, stream>>>(
          cur, wb, cb[li + 1], oth, nullptr, zp, c.cin, c.cs, c.cout, c.H, c.W, NHW);
    } else if (li <= 8) {
      // 28x28, N=512: split-K=2, 8-wave wide-N tile (392 WGs; REVERT)
      conv_gemm<128, 256, 2, 4, 2><<<dim3((NHW + 127) / 128, c.cout / 256, 2), 512, 0, stream>>>(
          cur, wb, cb[li + 1], nullptr, PS, zp, c.cin, c.cs, c.cout, c.H, c.W, NHW);
      if (fusedPool) {
        long pt = ((long)NHW / 4) * c.cout;
        reduce_split<2, true><<<(int)((pt / 4 + 255) / 256), 256, 0, stream>>>(
            PS, cb[li + 1], oth, NHW, c.H, c.W, c.cout);
      } else {
        long tot = (long)NHW * c.cout;
        reduce_split<2, false><<<(int)((tot / 4 + 255) / 256), 256, 0, stream>>>(
            PS, cb[li + 1], oth, NHW, c.H, c.W, c.cout);
      }
    } else {
      // 14x14, N=512: split-K=4 -> 400 WGs + reduce (fused pool on L11)
      conv_gemm<128, 128, 2, 2, 4><<<dim3((NHW + 127) / 128, c.cout / 128, 4), 256, 0, stream>>>(
          cur, wb, cb[li + 1], nullptr, PS, zp, c.cin, c.cs, c.cout, c.H, c.W, NHW);
      if (fusedPool) {
        long pt = ((long)NHW / 4) * c.cout;
        reduce_split<4, true><<<(int)((pt / 4 + 255) / 256), 256, 0, stream>>>(
            PS, cb[li + 1], oth, NHW, c.H, c.W, c.cout);
      } else {
        long tot = (long)NHW * c.cout;
        reduce_split<4, false><<<(int)((tot / 4 + 255) / 256), 256, 0, stream>>>(
            PS, cb[li + 1], oth, NHW, c.H, c.W, c.cout);
      }
    }
    bf16* t = cur; cur = oth; oth = t;
    if (poolAfter[li] && !fusedPool) {
      int cs3 = (c.cout == 64) ? 3 : (c.cout == 128) ? 4 : (c.cout == 256) ? 5 : 6;
      int W2 = c.W / 2, H2 = c.H / 2;
      int WC8 = W2 << cs3;
      maxpool_nhwc<<<dim3((WC8 + 255) / 256, H2, 16), 256, 0, stream>>>(cur, oth, c.H, c.W, c.cout, cs3, WC8);
      t = cur; cur = oth; oth = t;
    }
  }
  // cur = pool5 output [16,7,7,512] NHWC bf16.
  float* P1 = (float*)oth;                                 // 196*16*4096*4 = 51.4 MB
  float* P2 = (float*)((char*)oth + 52u * 1024 * 1024);    // 128*16*4096*4 = 33.6 MB
  float* P3 = (float*)((char*)oth + 89u * 1024 * 1024);    // 128*16*1000*4 =  8.2 MB

  fc1_partial<<<dim3(4, 196), 256, 0, stream>>>(cur, fw1, P1);
  reduce_fc<<<(16 * 4096 + 255) / 256, 256, 0, stream>>>(P1, fb1, F1, 196, 4096, 16 * 4096);
  fc23_partial<32><<<dim3(4, 128), 256, 0, stream>>>(F1, fw2, P2, 4096, 4096);
  reduce_fc<<<(16 * 4096 + 255) / 256, 256, 0, stream>>>(P2, fb2, F2, 128, 4096, 16 * 4096);
  fc23_partial<32><<<dim3(1, 128), 256, 0, stream>>>(F2, fw3, P3, 4096, 1000);
  reduce_fc<<<(16 * 1000 + 255) / 256, 256, 0, stream>>>(P3, fb3, outp, 128, 1000, 16 * 1000);
}